// Round 10
// baseline (339.432 us; speedup 1.0000x reference)
//
#include <hip/hip_runtime.h>
#include <hip/hip_fp16.h>

// Problem: B=8, N=2048, D=1024, ATT=128   (all I/O float32)
//   f = x@Wf + bf ; g = x@Wg + bg ; out = softmax(f g^T) @ x + x
// Round 12 (resubmit; r9 infra-fail): r8 validated the split (conflicts=0,
// pv latency-bound at 985 cyc/iter vs 307 MFMA; attp ~77us at 1 block/CU).
//  - pv: 3-deep DMA ring (48KB LDS, 3 blocks/CU) + raw s_barrier with
//    COUNTED vmcnt(4): the batch drained at each barrier was issued a FULL
//    iteration earlier (~2000cyc to land), not the same iter. T4 proper.
//    Ring audit: outstanding at barrier = 8, vmcnt(4) drains exactly the
//    batch read next iter; WAR closed by lgkm drain + barrier of t-1.
//  - attp: block 256thr/4 waves (each wave = one 512-key quarter of the
//    same 16 q rows), grid (N/16,B)=1024 = 4 blocks/CU; next-iter g-frags
//    register-double-buffered ahead of the MFMA+exp cluster (2x unroll,
//    static indexing).

#define B_ 8
#define N_ 2048
#define D_ 1024
#define A_ 128

typedef _Float16 half8v  __attribute__((ext_vector_type(8)));
typedef _Float16 half4v  __attribute__((ext_vector_type(4)));
typedef short    short8v __attribute__((ext_vector_type(8)));
typedef float    floatx4 __attribute__((ext_vector_type(4)));

#define SOFT_C 44.0f

__device__ __forceinline__ floatx4 mfma32(half8v a, half8v b, floatx4 c) {
#if defined(__HIP_DEVICE_COMPILE__)
    return __builtin_amdgcn_mfma_f32_16x16x32_f16(a, b, c, 0, 0, 0);
#else
    return c;
#endif
}
__device__ __forceinline__ floatx4 mfma32bf(short8v a, short8v b, floatx4 c) {
#if defined(__HIP_DEVICE_COMPILE__)
    return __builtin_amdgcn_mfma_f32_16x16x32_bf16(a, b, c, 0, 0, 0);
#else
    return c;
#endif
}

// f32 -> bf16 (RNE)
__device__ __forceinline__ unsigned short f2bf(float x) {
    union { float f; unsigned int u; } v; v.f = x;
    unsigned int u = v.u + 0x7fffu + ((v.u >> 16) & 1u);
    return (unsigned short)(u >> 16);
}

// 16B global -> LDS DMA. Dest is wave-uniform base (+lane*16 by HW).
__device__ __forceinline__ void gload_lds16(const void* gsrc, void* ldst) {
#if defined(__HIP_DEVICE_COMPILE__)
    __builtin_amdgcn_global_load_lds(
        (const __attribute__((address_space(1))) void*)gsrc,
        (__attribute__((address_space(3))) void*)ldst, 16, 0, 0);
#endif
}

// ---------------------------------------------------------------------------
// Kernel 0: transpose+convert x [b][n][d] fp32 -> xT [b][d][n] BF16.
// ---------------------------------------------------------------------------
__global__ __launch_bounds__(256) void xpose_kernel(
    const float* __restrict__ x, unsigned short* __restrict__ xT)
{
    __shared__ __align__(16) unsigned short ts[64][80];
    const int n0 = blockIdx.x * 64, d0 = blockIdx.y * 64, b = blockIdx.z;
    const int t = threadIdx.x;
#pragma unroll
    for (int s = 0; s < 4; ++s) {
        int idx = t + 256 * s;
        int nl = idx >> 4, c4 = idx & 15;
        float4 v = ((const float4*)(x + ((size_t)(b * N_ + n0 + nl)) * D_ + d0))[c4];
        ts[c4 * 4 + 0][nl] = f2bf(v.x);
        ts[c4 * 4 + 1][nl] = f2bf(v.y);
        ts[c4 * 4 + 2][nl] = f2bf(v.z);
        ts[c4 * 4 + 3][nl] = f2bf(v.w);
    }
    __syncthreads();
#pragma unroll
    for (int s = 0; s < 2; ++s) {
        int idx = t + 256 * s;
        int dl = idx >> 3, c = idx & 7;
        *(uint4*)&xT[((size_t)b * D_ + d0 + dl) * N_ + n0 + c * 8] =
            *(const uint4*)&ts[dl][c * 8];
    }
}

// ---------------------------------------------------------------------------
// Kernel 0b: W [1024][128] f32 -> whT [2][128][1024] f16 (transposed, K-major)
// ---------------------------------------------------------------------------
__global__ __launch_bounds__(256) void wprep_kernel(
    const float* __restrict__ Wf, const float* __restrict__ Wg,
    _Float16* __restrict__ whT)
{
    __shared__ __align__(16) _Float16 ts[64][72];
    const int k0 = blockIdx.x * 64, c0 = blockIdx.y * 64;
    const float* W = blockIdx.z ? Wg : Wf;
    _Float16* dst = whT + (size_t)blockIdx.z * A_ * D_;
    const int t = threadIdx.x;
#pragma unroll
    for (int s = 0; s < 4; ++s) {
        int idx = t + 256 * s;
        int kl = idx >> 4, c4 = idx & 15;
        float4 v = *(const float4*)&W[(size_t)(k0 + kl) * A_ + c0 + c4 * 4];
        ts[c4 * 4 + 0][kl] = (_Float16)v.x;
        ts[c4 * 4 + 1][kl] = (_Float16)v.y;
        ts[c4 * 4 + 2][kl] = (_Float16)v.z;
        ts[c4 * 4 + 3][kl] = (_Float16)v.w;
    }
    __syncthreads();
#pragma unroll
    for (int s = 0; s < 2; ++s) {
        int idx = t + 256 * s;
        int cl = idx >> 3, ch = idx & 7;
        *(uint4*)&dst[(size_t)(c0 + cl) * D_ + k0 + ch * 8] =
            *(const uint4*)&ts[cl][ch * 8];
    }
}

// ---------------------------------------------------------------------------
// Kernel 1: MFMA GEMM, f AND g per block (x staged once). Unchanged.
// ---------------------------------------------------------------------------
__global__ __launch_bounds__(256) void fgmm_kernel(
    const float* __restrict__ x, const _Float16* __restrict__ whT,
    const float* __restrict__ bfv, const float* __restrict__ bgv,
    _Float16* __restrict__ fh, _Float16* __restrict__ gh)
{
    __shared__ __align__(16) _Float16 xs[64 * 40];
    __shared__ __align__(16) _Float16 wt[256 * 40];
    const int row0 = blockIdx.x * 64;
    const int t = threadIdx.x;
    const int w = t >> 6, lane = t & 63, quad = lane >> 4, l16 = lane & 15;
    const int wr  = (w >> 1) * 32;
    const int wch = (w & 1);

    float4 xRf[2];
    uint4  wR[4];
#define FG_LOAD_TILE(K0)                                                      \
    {                                                                         \
        _Pragma("unroll")                                                     \
        for (int s = 0; s < 2; ++s) {                                         \
            int idx = t + 256 * s;                                            \
            int r = idx >> 3, k4 = idx & 7;                                   \
            xRf[s] = *(const float4*)&x[(size_t)(row0 + r) * D_ + (K0) + k4 * 4]; \
        }                                                                     \
        _Pragma("unroll")                                                     \
        for (int s = 0; s < 4; ++s) {                                         \
            int idx = t + 256 * s;                                            \
            int c = idx >> 2, k8 = idx & 3;                                   \
            wR[s] = *(const uint4*)&whT[(size_t)c * D_ + (K0) + k8 * 8];      \
        }                                                                     \
    }

    FG_LOAD_TILE(0)

    floatx4 acc[2][8];
#pragma unroll
    for (int ms = 0; ms < 2; ++ms)
#pragma unroll
        for (int nt = 0; nt < 8; ++nt)
            acc[ms][nt] = (floatx4){0.f, 0.f, 0.f, 0.f};

    for (int kt = 0; kt < 32; ++kt) {
        __syncthreads();
#pragma unroll
        for (int s = 0; s < 2; ++s) {
            int idx = t + 256 * s;
            int r = idx >> 3, k4 = idx & 7;
            half4v h = {(_Float16)xRf[s].x, (_Float16)xRf[s].y,
                        (_Float16)xRf[s].z, (_Float16)xRf[s].w};
            *(half4v*)&xs[r * 40 + k4 * 4] = h;
        }
#pragma unroll
        for (int s = 0; s < 4; ++s) {
            int idx = t + 256 * s;
            int c = idx >> 2, k8 = idx & 3;
            *(uint4*)&wt[c * 40 + k8 * 8] = wR[s];
        }
        __syncthreads();
        if (kt < 31) FG_LOAD_TILE((kt + 1) * 32)

        half8v a0 = *(const half8v*)&xs[(wr + l16) * 40 + quad * 8];
        half8v a1 = *(const half8v*)&xs[(wr + 16 + l16) * 40 + quad * 8];
#pragma unroll
        for (int nt = 0; nt < 8; ++nt) {
            half8v bfr = *(const half8v*)&wt[(wch * 128 + nt * 16 + l16) * 40 + quad * 8];
            acc[0][nt] = mfma32(a0, bfr, acc[0][nt]);
            acc[1][nt] = mfma32(a1, bfr, acc[1][nt]);
        }
    }

    _Float16* dst = wch ? gh : fh;
    const float* bias = wch ? bgv : bfv;
#pragma unroll
    for (int nt = 0; nt < 8; ++nt) {
        int col = nt * 16 + l16;
        float bv = bias[col];
#pragma unroll
        for (int ms = 0; ms < 2; ++ms)
#pragma unroll
            for (int rg = 0; rg < 4; ++rg) {
                int row = row0 + wr + ms * 16 + quad * 4 + rg;
                dst[(size_t)row * A_ + col] = (_Float16)(acc[ms][nt][rg] + bv);
            }
    }
}

// ---------------------------------------------------------------------------
// Kernel 2a: attp — QK + single-pass max-free softmax -> P_hat (bf16), lsum.
// Block 256 thr = 4 waves; each wave owns key-quarter kbase=wave*512 of the
// SAME 16 q rows (q0 = blockIdx.x*16). Grid (N/16, B) = 1024 blocks
// -> 4 blocks/CU (was 1). Next-iter g A-frags register-double-buffered
// (issued before current MFMA+exp cluster; 2x-unrolled ping-pong).
// ---------------------------------------------------------------------------
__global__ __launch_bounds__(256) void attp_kernel(
    const _Float16* __restrict__ f, const _Float16* __restrict__ g,
    unsigned short* __restrict__ P, float* __restrict__ lsum)
{
    __shared__ __align__(16) unsigned short tps[4][16 * 56]; // per-wave slab
    __shared__ float lred[4][16];

    const int tid = threadIdx.x;
    const int wave = tid >> 6, lane = tid & 63;
    const int quad = lane >> 4, l16 = lane & 15;
    const int q0 = blockIdx.x * 16;
    const int b  = blockIdx.y;
    const int kbase = wave * 512;

    // f B-frags for the block's 16 q rows: B[row=q=l16][k=quad*8+j]
    half8v fb[4];
#pragma unroll
    for (int kc = 0; kc < 4; ++kc)
        fb[kc] = *(const half8v*)(f +
            ((size_t)(b * N_ + q0 + l16)) * A_ + kc * 32 + quad * 8);

    unsigned short* slab = &tps[wave][0];
    float l_part = 0.f;

#define ATTP_LOADG(A0, A1, M0)                                                \
    {                                                                         \
        _Pragma("unroll")                                                     \
        for (int kc = 0; kc < 4; ++kc) {                                      \
            A0[kc] = *(const half8v*)(g +                                     \
                ((size_t)(b * N_ + (M0) + l16)) * A_ + kc * 32 + quad * 8);   \
            A1[kc] = *(const half8v*)(g +                                     \
                ((size_t)(b * N_ + (M0) + 16 + l16)) * A_ + kc * 32 + quad * 8); \
        }                                                                     \
    }

#define ATTP_COMPUTE(A0, A1, TT)                                              \
    {                                                                         \
        const int m0 = kbase + (TT) * 32;                                     \
        floatx4 sc0 = (floatx4){0.f, 0.f, 0.f, 0.f};                          \
        floatx4 sc1 = (floatx4){0.f, 0.f, 0.f, 0.f};                          \
        _Pragma("unroll")                                                     \
        for (int kc = 0; kc < 4; ++kc) {                                      \
            sc0 = mfma32(A0[kc], fb[kc], sc0);                                \
            sc1 = mfma32(A1[kc], fb[kc], sc1);                                \
        }                                                                     \
        float e0 = __expf(sc0[0] - SOFT_C), e1 = __expf(sc0[1] - SOFT_C);     \
        float e2 = __expf(sc0[2] - SOFT_C), e3 = __expf(sc0[3] - SOFT_C);     \
        float e4 = __expf(sc1[0] - SOFT_C), e5 = __expf(sc1[1] - SOFT_C);     \
        float e6 = __expf(sc1[2] - SOFT_C), e7 = __expf(sc1[3] - SOFT_C);     \
        l_part += ((e0 + e1) + (e2 + e3)) + ((e4 + e5) + (e6 + e7));          \
        unsigned int w01 = (unsigned int)f2bf(e0) | ((unsigned int)f2bf(e1) << 16); \
        unsigned int w23 = (unsigned int)f2bf(e2) | ((unsigned int)f2bf(e3) << 16); \
        unsigned int w45 = (unsigned int)f2bf(e4) | ((unsigned int)f2bf(e5) << 16); \
        unsigned int w67 = (unsigned int)f2bf(e6) | ((unsigned int)f2bf(e7) << 16); \
        *(unsigned int*)&slab[l16 * 56 + quad * 4]          = w01;            \
        *(unsigned int*)&slab[l16 * 56 + quad * 4 + 2]      = w23;            \
        *(unsigned int*)&slab[l16 * 56 + 16 + quad * 4]     = w45;            \
        *(unsigned int*)&slab[l16 * 56 + 16 + quad * 4 + 2] = w67;            \
        asm volatile("s_waitcnt lgkmcnt(0)" ::: "memory");                    \
        __builtin_amdgcn_sched_barrier(0);                                    \
        uint4 pvv = *(const uint4*)&slab[(lane >> 2) * 56 + (lane & 3) * 8];  \
        *(uint4*)(P + ((size_t)(b * N_ + q0 + (lane >> 2))) * N_ +            \
                  m0 + (lane & 3) * 8) = pvv;                                 \
    }

    half8v ga0[4], ga1[4], gb0[4], gb1[4];
    ATTP_LOADG(ga0, ga1, kbase)
#pragma unroll 1
    for (int tp = 0; tp < 8; ++tp) {
        ATTP_LOADG(gb0, gb1, kbase + (tp * 2 + 1) * 32)
        ATTP_COMPUTE(ga0, ga1, tp * 2)
        if (tp < 7) ATTP_LOADG(ga0, ga1, kbase + (tp * 2 + 2) * 32)
        ATTP_COMPUTE(gb0, gb1, tp * 2 + 1)
    }

    // l reduce over quad halves, then merge the 4 key-quarters
    l_part += __shfl_xor(l_part, 16);
    l_part += __shfl_xor(l_part, 32);
    if (lane < 16) lred[wave][lane] = l_part;
    __syncthreads();
    if (wave == 0 && lane < 16)
        lsum[(size_t)b * N_ + q0 + lane] =
            (lred[0][lane] + lred[1][lane]) + (lred[2][lane] + lred[3][lane]);
}

// ---------------------------------------------------------------------------
// Kernel 2b: pv — out = (P_hat @ x) * (1/l) + x.  128x128xK=2048 bf16 GEMM.
// 3-deep DMA ring (A/B/C, 48KB -> 3 blocks/CU), raw s_barrier + COUNTED
// vmcnt(4): the batch waited on at each barrier was issued a full iteration
// earlier (~2 iters in flight). Chunk-XOR swizzle (conflict-free, r8: 0).
// Ring safety: stage(t+2) writes buf[(t+2)%3] = buf[(t-1)%3], whose reads
// were lgkm-drained before the barrier ending iter t-1.
// ---------------------------------------------------------------------------
__global__ __launch_bounds__(256, 3) void pv_kernel(
    const unsigned short* __restrict__ P, const unsigned short* __restrict__ xT,
    const float* __restrict__ lsum, const float* __restrict__ x,
    float* __restrict__ out)
{
    __shared__ __align__(16) unsigned short Ps[3][128 * 32];
    __shared__ __align__(16) unsigned short Xs[3][128 * 32];

    const int bm = blockIdx.x;          // q-tile  (N/128)
    const int dn = blockIdx.y;          // d-tile  (D/128)
    const int b  = blockIdx.z;
    const int tid = threadIdx.x;
    const int wave = tid >> 6, lane = tid & 63;
    const int quad = lane >> 4, l16 = lane & 15;
    const int wm = wave >> 1, wn = wave & 1;   // 2x2 wave grid, 64x64 each
    const int xorv = (l16 >> 1) & 3;
    const int chq = (quad ^ xorv) * 8;

#define PV_STAGE(BUF, T0)                                                     \
    {                                                                         \
        _Pragma("unroll")                                                     \
        for (int s = 0; s < 2; ++s) {                                         \
            int idx = s * 256 + tid;                                          \
            int row = idx >> 2, c = idx & 3;                                  \
            int cc = c ^ ((row >> 1) & 3);                                    \
            gload_lds16(P + ((size_t)(b * N_ + bm * 128 + row)) * N_ +        \
                            (T0) + cc * 8,                                    \
                        &Ps[BUF][(s * 256 + wave * 64) * 8]);                 \
        }                                                                     \
        _Pragma("unroll")                                                     \
        for (int s = 0; s < 2; ++s) {                                         \
            int idx = s * 256 + tid;                                          \
            int row = idx >> 2, c = idx & 3;                                  \
            int cc = c ^ ((row >> 1) & 3);                                    \
            gload_lds16(xT + ((size_t)(b * D_ + dn * 128 + row)) * N_ +       \
                            (T0) + cc * 8,                                    \
                        &Xs[BUF][(s * 256 + wave * 64) * 8]);                 \
        }                                                                     \
    }

    floatx4 acc[4][4];
#pragma unroll
    for (int m = 0; m < 4; ++m)
#pragma unroll
        for (int n = 0; n < 4; ++n)
            acc[m][n] = (floatx4){0.f, 0.f, 0.f, 0.f};

    // prologue: tiles 0,1 in flight; wait for tile 0 only (leave 1 in flight)
    PV_STAGE(0, 0)
    PV_STAGE(1, 32)
    asm volatile("s_waitcnt vmcnt(4)" ::: "memory");
    __builtin_amdgcn_sched_barrier(0);
    __builtin_amdgcn_s_barrier();

    int cur = 0;
    for (int t = 0; t < 64; ++t) {
        int nx2 = cur + 2; if (nx2 >= 3) nx2 -= 3;
        if (t < 62) PV_STAGE(nx2, (t + 2) * 32)

        short8v a[4], bb[4];
#pragma unroll
        for (int m = 0; m < 4; ++m)
            a[m] = *(const short8v*)&Ps[cur][(wm * 64 + m * 16 + l16) * 32 + chq];
#pragma unroll
        for (int n = 0; n < 4; ++n)
            bb[n] = *(const short8v*)&Xs[cur][(wn * 64 + n * 16 + l16) * 32 + chq];

        __builtin_amdgcn_s_setprio(1);
#pragma unroll
        for (int m = 0; m < 4; ++m)
#pragma unroll
            for (int n = 0; n < 4; ++n)
                acc[m][n] = mfma32bf(a[m], bb[n], acc[m][n]);
        __builtin_amdgcn_s_setprio(0);

        if (t < 63) {
            // drain: my ds_reads (WAR) + the DMA batch issued LAST iter (RAW
            // for buf[(t+1)%3]); this iter's batch (4 ops) stays in flight.
            asm volatile("s_waitcnt lgkmcnt(0)" ::: "memory");
            if (t < 62) {
                asm volatile("s_waitcnt vmcnt(4)" ::: "memory");
            } else {
                asm volatile("s_waitcnt vmcnt(0)" ::: "memory");
            }
            __builtin_amdgcn_sched_barrier(0);
            __builtin_amdgcn_s_barrier();
            __builtin_amdgcn_sched_barrier(0);
        }
        cur = (cur == 2) ? 0 : cur + 1;
    }

    // epilogue: out = acc/l + x
    float linv[4][4];
#pragma unroll
    for (int m = 0; m < 4; ++m)
#pragma unroll
        for (int rg = 0; rg < 4; ++rg) {
            int row = bm * 128 + wm * 64 + m * 16 + quad * 4 + rg;
            linv[m][rg] = 1.0f / lsum[(size_t)b * N_ + row];
        }
#pragma unroll
    for (int m = 0; m < 4; ++m)
#pragma unroll
        for (int rg = 0; rg < 4; ++rg) {
            int row = bm * 128 + wm * 64 + m * 16 + quad * 4 + rg;
            const size_t rowoff = ((size_t)(b * N_ + row)) * D_ + dn * 128;
#pragma unroll
            for (int n = 0; n < 4; ++n) {
                int col = wn * 64 + n * 16 + l16;
                out[rowoff + col] =
                    fmaf(acc[m][n][rg], linv[m][rg], x[rowoff + col]);
            }
        }
}

extern "C" void kernel_launch(void* const* d_in, const int* in_sizes, int n_in,
                              void* d_out, int out_size, void* d_ws, size_t ws_size,
                              hipStream_t stream) {
    const float* x   = (const float*)d_in[0];
    const float* Wf  = (const float*)d_in[1];
    const float* bfv = (const float*)d_in[2];
    const float* Wg  = (const float*)d_in[3];
    const float* bgv = (const float*)d_in[4];
    float* out = (float*)d_out;

    // ws layout (16-bit elems unless noted):
    //  fh[2.1M] gh[2.1M] xT[16.8M bf16] whT[0.26M] P[33.6M bf16] lsum[16K f32]
    _Float16*       fh  = (_Float16*)d_ws;
    _Float16*       gh  = fh + (size_t)B_ * N_ * A_;
    unsigned short* xT  = (unsigned short*)(gh + (size_t)B_ * N_ * A_);
    _Float16*       whT = (_Float16*)(xT + (size_t)B_ * D_ * N_);
    unsigned short* P   = (unsigned short*)(whT + (size_t)2 * A_ * D_);
    float*          lsum = (float*)(P + (size_t)B_ * N_ * N_);

    hipLaunchKernelGGL(xpose_kernel, dim3(N_ / 64, D_ / 64, B_), dim3(256), 0, stream,
                       x, xT);
    hipLaunchKernelGGL(wprep_kernel, dim3(D_ / 64, A_ / 64, 2), dim3(256), 0, stream,
                       Wf, Wg, whT);
    hipLaunchKernelGGL(fgmm_kernel, dim3(B_ * N_ / 64), dim3(256), 0, stream,
                       x, whT, bfv, bgv, fh, gh);
    hipLaunchKernelGGL(attp_kernel, dim3(N_ / 16, B_), dim3(256), 0, stream,
                       fh, gh, P, lsum);
    hipLaunchKernelGGL(pv_kernel, dim3(N_ / 128, D_ / 128, B_), dim3(256), 0, stream,
                       P, xT, lsum, x, out);
}

// Round 12
// 313.676 us; speedup vs baseline: 1.0821x; 1.0821x over previous
//
#include <hip/hip_runtime.h>
#include <hip/hip_fp16.h>

// Problem: B=8, N=2048, D=1024, ATT=128   (all I/O float32)
//   f = x@Wf + bf ; g = x@Wg + bg ; out = softmax(f g^T) @ x + x
// Round 13 (resubmit; r11 infra-fail): fix r10's pv regression. Ring-3
// pipeline WORKED mechanically but 48KB LDS -> 3 blocks/CU resident vs grid
// 4/CU -> residency quantization (measured occupancy 23% = time-avg 2/CU).
// New pv: BM x BN = 128x256, 8 waves (512 thr, 2x4 wave grid, 64x64/wave):
//   grid 512 = EXACTLY 2/CU; ring-3 LDS 72KB = EXACTLY 2 resident/CU.
//   16 waves/CU (4/SIMD). Logical P re-reads halve (D/BN 8->4).
//   Stage = 3 DMA/thread -> counted vmcnt(3) drains the batch issued a
//   full iteration ago. Same proven chunk-XOR swizzle (r8: conflicts=0).
// attp/fgmm/xpose unchanged for attribution.

#define B_ 8
#define N_ 2048
#define D_ 1024
#define A_ 128

typedef _Float16 half8v  __attribute__((ext_vector_type(8)));
typedef _Float16 half4v  __attribute__((ext_vector_type(4)));
typedef short    short8v __attribute__((ext_vector_type(8)));
typedef float    floatx4 __attribute__((ext_vector_type(4)));

#define SOFT_C 44.0f

__device__ __forceinline__ floatx4 mfma32(half8v a, half8v b, floatx4 c) {
#if defined(__HIP_DEVICE_COMPILE__)
    return __builtin_amdgcn_mfma_f32_16x16x32_f16(a, b, c, 0, 0, 0);
#else
    return c;
#endif
}
__device__ __forceinline__ floatx4 mfma32bf(short8v a, short8v b, floatx4 c) {
#if defined(__HIP_DEVICE_COMPILE__)
    return __builtin_amdgcn_mfma_f32_16x16x32_bf16(a, b, c, 0, 0, 0);
#else
    return c;
#endif
}

// f32 -> bf16 (RNE)
__device__ __forceinline__ unsigned short f2bf(float x) {
    union { float f; unsigned int u; } v; v.f = x;
    unsigned int u = v.u + 0x7fffu + ((v.u >> 16) & 1u);
    return (unsigned short)(u >> 16);
}

// 16B global -> LDS DMA. Dest is wave-uniform base (+lane*16 by HW).
__device__ __forceinline__ void gload_lds16(const void* gsrc, void* ldst) {
#if defined(__HIP_DEVICE_COMPILE__)
    __builtin_amdgcn_global_load_lds(
        (const __attribute__((address_space(1))) void*)gsrc,
        (__attribute__((address_space(3))) void*)ldst, 16, 0, 0);
#endif
}

// ---------------------------------------------------------------------------
// Kernel 0: transpose+convert x [b][n][d] fp32 -> xT [b][d][n] BF16.
// ---------------------------------------------------------------------------
__global__ __launch_bounds__(256) void xpose_kernel(
    const float* __restrict__ x, unsigned short* __restrict__ xT)
{
    __shared__ __align__(16) unsigned short ts[64][80];
    const int n0 = blockIdx.x * 64, d0 = blockIdx.y * 64, b = blockIdx.z;
    const int t = threadIdx.x;
#pragma unroll
    for (int s = 0; s < 4; ++s) {
        int idx = t + 256 * s;
        int nl = idx >> 4, c4 = idx & 15;
        float4 v = ((const float4*)(x + ((size_t)(b * N_ + n0 + nl)) * D_ + d0))[c4];
        ts[c4 * 4 + 0][nl] = f2bf(v.x);
        ts[c4 * 4 + 1][nl] = f2bf(v.y);
        ts[c4 * 4 + 2][nl] = f2bf(v.z);
        ts[c4 * 4 + 3][nl] = f2bf(v.w);
    }
    __syncthreads();
#pragma unroll
    for (int s = 0; s < 2; ++s) {
        int idx = t + 256 * s;
        int dl = idx >> 3, c = idx & 7;
        *(uint4*)&xT[((size_t)b * D_ + d0 + dl) * N_ + n0 + c * 8] =
            *(const uint4*)&ts[dl][c * 8];
    }
}

// ---------------------------------------------------------------------------
// Kernel 0b: W [1024][128] f32 -> whT [2][128][1024] f16 (transposed, K-major)
// ---------------------------------------------------------------------------
__global__ __launch_bounds__(256) void wprep_kernel(
    const float* __restrict__ Wf, const float* __restrict__ Wg,
    _Float16* __restrict__ whT)
{
    __shared__ __align__(16) _Float16 ts[64][72];
    const int k0 = blockIdx.x * 64, c0 = blockIdx.y * 64;
    const float* W = blockIdx.z ? Wg : Wf;
    _Float16* dst = whT + (size_t)blockIdx.z * A_ * D_;
    const int t = threadIdx.x;
#pragma unroll
    for (int s = 0; s < 4; ++s) {
        int idx = t + 256 * s;
        int kl = idx >> 4, c4 = idx & 15;
        float4 v = *(const float4*)&W[(size_t)(k0 + kl) * A_ + c0 + c4 * 4];
        ts[c4 * 4 + 0][kl] = (_Float16)v.x;
        ts[c4 * 4 + 1][kl] = (_Float16)v.y;
        ts[c4 * 4 + 2][kl] = (_Float16)v.z;
        ts[c4 * 4 + 3][kl] = (_Float16)v.w;
    }
    __syncthreads();
#pragma unroll
    for (int s = 0; s < 2; ++s) {
        int idx = t + 256 * s;
        int cl = idx >> 3, ch = idx & 7;
        *(uint4*)&dst[(size_t)(c0 + cl) * D_ + k0 + ch * 8] =
            *(const uint4*)&ts[cl][ch * 8];
    }
}

// ---------------------------------------------------------------------------
// Kernel 1: MFMA GEMM, f AND g per block (x staged once). Unchanged.
// ---------------------------------------------------------------------------
__global__ __launch_bounds__(256) void fgmm_kernel(
    const float* __restrict__ x, const _Float16* __restrict__ whT,
    const float* __restrict__ bfv, const float* __restrict__ bgv,
    _Float16* __restrict__ fh, _Float16* __restrict__ gh)
{
    __shared__ __align__(16) _Float16 xs[64 * 40];
    __shared__ __align__(16) _Float16 wt[256 * 40];
    const int row0 = blockIdx.x * 64;
    const int t = threadIdx.x;
    const int w = t >> 6, lane = t & 63, quad = lane >> 4, l16 = lane & 15;
    const int wr  = (w >> 1) * 32;
    const int wch = (w & 1);

    float4 xRf[2];
    uint4  wR[4];
#define FG_LOAD_TILE(K0)                                                      \
    {                                                                         \
        _Pragma("unroll")                                                     \
        for (int s = 0; s < 2; ++s) {                                         \
            int idx = t + 256 * s;                                            \
            int r = idx >> 3, k4 = idx & 7;                                   \
            xRf[s] = *(const float4*)&x[(size_t)(row0 + r) * D_ + (K0) + k4 * 4]; \
        }                                                                     \
        _Pragma("unroll")                                                     \
        for (int s = 0; s < 4; ++s) {                                         \
            int idx = t + 256 * s;                                            \
            int c = idx >> 2, k8 = idx & 3;                                   \
            wR[s] = *(const uint4*)&whT[(size_t)c * D_ + (K0) + k8 * 8];      \
        }                                                                     \
    }

    FG_LOAD_TILE(0)

    floatx4 acc[2][8];
#pragma unroll
    for (int ms = 0; ms < 2; ++ms)
#pragma unroll
        for (int nt = 0; nt < 8; ++nt)
            acc[ms][nt] = (floatx4){0.f, 0.f, 0.f, 0.f};

    for (int kt = 0; kt < 32; ++kt) {
        __syncthreads();
#pragma unroll
        for (int s = 0; s < 2; ++s) {
            int idx = t + 256 * s;
            int r = idx >> 3, k4 = idx & 7;
            half4v h = {(_Float16)xRf[s].x, (_Float16)xRf[s].y,
                        (_Float16)xRf[s].z, (_Float16)xRf[s].w};
            *(half4v*)&xs[r * 40 + k4 * 4] = h;
        }
#pragma unroll
        for (int s = 0; s < 4; ++s) {
            int idx = t + 256 * s;
            int c = idx >> 2, k8 = idx & 3;
            *(uint4*)&wt[c * 40 + k8 * 8] = wR[s];
        }
        __syncthreads();
        if (kt < 31) FG_LOAD_TILE((kt + 1) * 32)

        half8v a0 = *(const half8v*)&xs[(wr + l16) * 40 + quad * 8];
        half8v a1 = *(const half8v*)&xs[(wr + 16 + l16) * 40 + quad * 8];
#pragma unroll
        for (int nt = 0; nt < 8; ++nt) {
            half8v bfr = *(const half8v*)&wt[(wch * 128 + nt * 16 + l16) * 40 + quad * 8];
            acc[0][nt] = mfma32(a0, bfr, acc[0][nt]);
            acc[1][nt] = mfma32(a1, bfr, acc[1][nt]);
        }
    }

    _Float16* dst = wch ? gh : fh;
    const float* bias = wch ? bgv : bfv;
#pragma unroll
    for (int nt = 0; nt < 8; ++nt) {
        int col = nt * 16 + l16;
        float bv = bias[col];
#pragma unroll
        for (int ms = 0; ms < 2; ++ms)
#pragma unroll
            for (int rg = 0; rg < 4; ++rg) {
                int row = row0 + wr + ms * 16 + quad * 4 + rg;
                dst[(size_t)row * A_ + col] = (_Float16)(acc[ms][nt][rg] + bv);
            }
    }
}

// ---------------------------------------------------------------------------
// Kernel 2a: attp — QK + single-pass max-free softmax -> P_hat (bf16), lsum.
// Unchanged from r12.
// ---------------------------------------------------------------------------
__global__ __launch_bounds__(256) void attp_kernel(
    const _Float16* __restrict__ f, const _Float16* __restrict__ g,
    unsigned short* __restrict__ P, float* __restrict__ lsum)
{
    __shared__ __align__(16) unsigned short tps[4][16 * 56]; // per-wave slab
    __shared__ float lred[4][16];

    const int tid = threadIdx.x;
    const int wave = tid >> 6, lane = tid & 63;
    const int quad = lane >> 4, l16 = lane & 15;
    const int q0 = blockIdx.x * 16;
    const int b  = blockIdx.y;
    const int kbase = wave * 512;

    // f B-frags for the block's 16 q rows: B[row=q=l16][k=quad*8+j]
    half8v fb[4];
#pragma unroll
    for (int kc = 0; kc < 4; ++kc)
        fb[kc] = *(const half8v*)(f +
            ((size_t)(b * N_ + q0 + l16)) * A_ + kc * 32 + quad * 8);

    unsigned short* slab = &tps[wave][0];
    float l_part = 0.f;

#define ATTP_LOADG(A0, A1, M0)                                                \
    {                                                                         \
        _Pragma("unroll")                                                     \
        for (int kc = 0; kc < 4; ++kc) {                                      \
            A0[kc] = *(const half8v*)(g +                                     \
                ((size_t)(b * N_ + (M0) + l16)) * A_ + kc * 32 + quad * 8);   \
            A1[kc] = *(const half8v*)(g +                                     \
                ((size_t)(b * N_ + (M0) + 16 + l16)) * A_ + kc * 32 + quad * 8); \
        }                                                                     \
    }

#define ATTP_COMPUTE(A0, A1, TT)                                              \
    {                                                                         \
        const int m0 = kbase + (TT) * 32;                                     \
        floatx4 sc0 = (floatx4){0.f, 0.f, 0.f, 0.f};                          \
        floatx4 sc1 = (floatx4){0.f, 0.f, 0.f, 0.f};                          \
        _Pragma("unroll")                                                     \
        for (int kc = 0; kc < 4; ++kc) {                                      \
            sc0 = mfma32(A0[kc], fb[kc], sc0);                                \
            sc1 = mfma32(A1[kc], fb[kc], sc1);                                \
        }                                                                     \
        float e0 = __expf(sc0[0] - SOFT_C), e1 = __expf(sc0[1] - SOFT_C);     \
        float e2 = __expf(sc0[2] - SOFT_C), e3 = __expf(sc0[3] - SOFT_C);     \
        float e4 = __expf(sc1[0] - SOFT_C), e5 = __expf(sc1[1] - SOFT_C);     \
        float e6 = __expf(sc1[2] - SOFT_C), e7 = __expf(sc1[3] - SOFT_C);     \
        l_part += ((e0 + e1) + (e2 + e3)) + ((e4 + e5) + (e6 + e7));          \
        unsigned int w01 = (unsigned int)f2bf(e0) | ((unsigned int)f2bf(e1) << 16); \
        unsigned int w23 = (unsigned int)f2bf(e2) | ((unsigned int)f2bf(e3) << 16); \
        unsigned int w45 = (unsigned int)f2bf(e4) | ((unsigned int)f2bf(e5) << 16); \
        unsigned int w67 = (unsigned int)f2bf(e6) | ((unsigned int)f2bf(e7) << 16); \
        *(unsigned int*)&slab[l16 * 56 + quad * 4]          = w01;            \
        *(unsigned int*)&slab[l16 * 56 + quad * 4 + 2]      = w23;            \
        *(unsigned int*)&slab[l16 * 56 + 16 + quad * 4]     = w45;            \
        *(unsigned int*)&slab[l16 * 56 + 16 + quad * 4 + 2] = w67;            \
        asm volatile("s_waitcnt lgkmcnt(0)" ::: "memory");                    \
        __builtin_amdgcn_sched_barrier(0);                                    \
        uint4 pvv = *(const uint4*)&slab[(lane >> 2) * 56 + (lane & 3) * 8];  \
        *(uint4*)(P + ((size_t)(b * N_ + q0 + (lane >> 2))) * N_ +            \
                  m0 + (lane & 3) * 8) = pvv;                                 \
    }

    half8v ga0[4], ga1[4], gb0[4], gb1[4];
    ATTP_LOADG(ga0, ga1, kbase)
#pragma unroll 1
    for (int tp = 0; tp < 8; ++tp) {
        ATTP_LOADG(gb0, gb1, kbase + (tp * 2 + 1) * 32)
        ATTP_COMPUTE(ga0, ga1, tp * 2)
        if (tp < 7) ATTP_LOADG(ga0, ga1, kbase + (tp * 2 + 2) * 32)
        ATTP_COMPUTE(gb0, gb1, tp * 2 + 1)
    }

    // l reduce over quad halves, then merge the 4 key-quarters
    l_part += __shfl_xor(l_part, 16);
    l_part += __shfl_xor(l_part, 32);
    if (lane < 16) lred[wave][lane] = l_part;
    __syncthreads();
    if (wave == 0 && lane < 16)
        lsum[(size_t)b * N_ + q0 + lane] =
            (lred[0][lane] + lred[1][lane]) + (lred[2][lane] + lred[3][lane]);
}

// ---------------------------------------------------------------------------
// Kernel 2b: pv — out = (P_hat @ x) * (1/l) + x.  128x256 tile, 8 waves
// (2x4 wave grid, 64x64/wave), K=2048 in 32-steps. 3-deep DMA ring:
// LDS = 3*(Ps 8KB + Xs 16KB) = 72KB -> EXACTLY 2 blocks/CU; grid
// (16,4,8)=512 = EXACTLY 2 blocks/CU -> no residency quantization.
// Stage = 3 DMA/thread; barrier waits lgkmcnt(0) (WAR) + vmcnt(3) (drains
// the batch issued a FULL iteration earlier; this iter's stays in flight).
// Chunk-XOR swizzle (r8-proven conflict-free).
// ---------------------------------------------------------------------------
__global__ __launch_bounds__(512, 4) void pv_kernel(
    const unsigned short* __restrict__ P, const unsigned short* __restrict__ xT,
    const float* __restrict__ lsum, const float* __restrict__ x,
    float* __restrict__ out)
{
    __shared__ __align__(16) unsigned short Ps[3][128 * 32];
    __shared__ __align__(16) unsigned short Xs[3][256 * 32];

    const int bm = blockIdx.x;          // q-tile  (N/128 = 16)
    const int dn = blockIdx.y;          // d-tile  (D/256 = 4)
    const int b  = blockIdx.z;
    const int tid = threadIdx.x;
    const int wave = tid >> 6, lane = tid & 63;
    const int quad = lane >> 4, l16 = lane & 15;
    const int wm = wave >> 2, wn = wave & 3;   // 2x4 wave grid, 64x64 each
    const int chq = (quad ^ ((l16 >> 1) & 3)) * 8;

#define PV_STAGE(BUF, T0)                                                     \
    {                                                                         \
        {                                                                     \
            int row = tid >> 2, c = tid & 3;                                  \
            int cc = c ^ ((row >> 1) & 3);                                    \
            gload_lds16(P + ((size_t)(b * N_ + bm * 128 + row)) * N_ +        \
                            (T0) + cc * 8,                                    \
                        &Ps[BUF][(wave * 64) * 8]);                           \
        }                                                                     \
        _Pragma("unroll")                                                     \
        for (int s = 0; s < 2; ++s) {                                         \
            int idx = s * 512 + tid;                                          \
            int row = idx >> 2, c = idx & 3;                                  \
            int cc = c ^ ((row >> 1) & 3);                                    \
            gload_lds16(xT + ((size_t)(b * D_ + dn * 256 + row)) * N_ +       \
                            (T0) + cc * 8,                                    \
                        &Xs[BUF][(s * 512 + wave * 64) * 8]);                 \
        }                                                                     \
    }

    floatx4 acc[4][4];
#pragma unroll
    for (int m = 0; m < 4; ++m)
#pragma unroll
        for (int n = 0; n < 4; ++n)
            acc[m][n] = (floatx4){0.f, 0.f, 0.f, 0.f};

    // prologue: tiles 0,1 in flight; drain batch 0 only (leave 1 in flight)
    PV_STAGE(0, 0)
    PV_STAGE(1, 32)
    asm volatile("s_waitcnt vmcnt(3)" ::: "memory");
    __builtin_amdgcn_sched_barrier(0);
    __builtin_amdgcn_s_barrier();

    int cur = 0;
    for (int t = 0; t < 64; ++t) {
        int nx2 = cur + 2; if (nx2 >= 3) nx2 -= 3;
        if (t < 62) PV_STAGE(nx2, (t + 2) * 32)

        short8v a[4], bb[4];
#pragma unroll
        for (int m = 0; m < 4; ++m)
            a[m] = *(const short8v*)&Ps[cur][(wm * 64 + m * 16 + l16) * 32 + chq];
#pragma unroll
        for (int n = 0; n < 4; ++n)
            bb[n] = *(const short8v*)&Xs[cur][(wn * 64 + n * 16 + l16) * 32 + chq];

        __builtin_amdgcn_s_setprio(1);
#pragma unroll
        for (int m = 0; m < 4; ++m)
#pragma unroll
            for (int n = 0; n < 4; ++n)
                acc[m][n] = mfma32bf(a[m], bb[n], acc[m][n]);
        __builtin_amdgcn_s_setprio(0);

        if (t < 63) {
            // WAR: my ds_reads of buf[cur] done; RAW: drain the DMA batch
            // issued LAST iter (next iter's buffer); this iter's stays out.
            asm volatile("s_waitcnt lgkmcnt(0)" ::: "memory");
            if (t < 62) {
                asm volatile("s_waitcnt vmcnt(3)" ::: "memory");
            } else {
                asm volatile("s_waitcnt vmcnt(0)" ::: "memory");
            }
            __builtin_amdgcn_sched_barrier(0);
            __builtin_amdgcn_s_barrier();
            __builtin_amdgcn_sched_barrier(0);
        }
        cur = (cur == 2) ? 0 : cur + 1;
    }

    // epilogue: out = acc/l + x
    float linv[4];
#pragma unroll
    for (int m = 0; m < 4; ++m) {
#pragma unroll
        for (int rg = 0; rg < 4; ++rg) {
            int row = bm * 128 + wm * 64 + m * 16 + quad * 4 + rg;
            linv[rg] = 1.0f / lsum[(size_t)b * N_ + row];
            const size_t rowoff = ((size_t)(b * N_ + row)) * D_ + dn * 256;
#pragma unroll
            for (int n = 0; n < 4; ++n) {
                int col = wn * 64 + n * 16 + l16;
                out[rowoff + col] =
                    fmaf(acc[m][n][rg], linv[rg], x[rowoff + col]);
            }
        }
    }
}

extern "C" void kernel_launch(void* const* d_in, const int* in_sizes, int n_in,
                              void* d_out, int out_size, void* d_ws, size_t ws_size,
                              hipStream_t stream) {
    const float* x   = (const float*)d_in[0];
    const float* Wf  = (const float*)d_in[1];
    const float* bfv = (const float*)d_in[2];
    const float* Wg  = (const float*)d_in[3];
    const float* bgv = (const float*)d_in[4];
    float* out = (float*)d_out;

    // ws layout (16-bit elems unless noted):
    //  fh[2.1M] gh[2.1M] xT[16.8M bf16] whT[0.26M] P[33.6M bf16] lsum[16K f32]
    _Float16*       fh  = (_Float16*)d_ws;
    _Float16*       gh  = fh + (size_t)B_ * N_ * A_;
    unsigned short* xT  = (unsigned short*)(gh + (size_t)B_ * N_ * A_);
    _Float16*       whT = (_Float16*)(xT + (size_t)B_ * D_ * N_);
    unsigned short* P   = (unsigned short*)(whT + (size_t)2 * A_ * D_);
    float*          lsum = (float*)(P + (size_t)B_ * N_ * N_);

    hipLaunchKernelGGL(xpose_kernel, dim3(N_ / 64, D_ / 64, B_), dim3(256), 0, stream,
                       x, xT);
    hipLaunchKernelGGL(wprep_kernel, dim3(D_ / 64, A_ / 64, 2), dim3(256), 0, stream,
                       Wf, Wg, whT);
    hipLaunchKernelGGL(fgmm_kernel, dim3(B_ * N_ / 64), dim3(256), 0, stream,
                       x, whT, bfv, bgv, fh, gh);
    hipLaunchKernelGGL(attp_kernel, dim3(N_ / 16, B_), dim3(256), 0, stream,
                       fh, gh, P, lsum);
    hipLaunchKernelGGL(pv_kernel, dim3(N_ / 128, D_ / 256, B_), dim3(512), 0, stream,
                       P, xT, lsum, x, out);
}